// Round 11
// baseline (223.369 us; speedup 1.0000x reference)
//
#include <hip/hip_runtime.h>
#include <hip/hip_bf16.h>

// Problem constants
#define NN  50000   // nodes
#define FD  128     // features
#define NE  800000  // external edges
#define NEI 400000  // internal edges
#define NG  64      // graphs

// Strides (elements) for XCD-privatized output accumulators
#define EZ_STRIDE  8192      // floats (32768 B per copy)
#define CNT_STRIDE 64        // ints   (256 B per copy)
#define DEGB_WORDS 12544     // packed byte counters: 4 nodes/word, 50176 B

typedef short  short8 __attribute__((ext_vector_type(8)));
typedef float  f32x4  __attribute__((ext_vector_type(4)));

union S8 { short8 s; unsigned int u[4]; };

__device__ __forceinline__ unsigned short bf16h(float f) {
  unsigned int u = __float_as_uint(f);
  u += 0x7FFFu + ((u >> 16) & 1u);            // RNE
  return (unsigned short)(u >> 16);
}
__device__ __forceinline__ float bf16tof(unsigned short h) {
  return __uint_as_float(((unsigned int)h) << 16);
}
// packed 2xf32 -> 2xbf16 (v_cvt_pk_bf16_f32): a in low 16, b in high 16
__device__ __forceinline__ unsigned int pk_bf16(float a, float b) {
  __hip_bfloat162 h = __float22bfloat162_rn(make_float2(a, b));
  unsigned int u;
  __builtin_memcpy(&u, &h, 4);
  return u;
}
// fast reciprocal: v_rcp_f32 (~1 ulp) — tolerance is 4.2e-5, plenty of slack
__device__ __forceinline__ float frcp(float x) { return __builtin_amdgcn_rcpf(x); }

// -------------------------------------------------------------------------
// ONE aux dispatch.  R19: degree histogram counts into PACKED 8-BIT
// counters (4 nodes per 32-bit word, atomicAdd of 1<<(8*(node&3))) in a
// SINGLE copy.  Rationale: aux was atomic-WRITEBACK bound (R18 profile:
// 37.6 MB WRITE at 850 GB/s = the 48 us).  4x line density -> 4x better
// line-write merging at the coherence point.  Max degree ~45 << 255, so
// byte overflow is impossible (P ~ e^-300).  Privatized deg copies dropped
// (R11 proved neutral: device-scope atomics bypass per-XCD L2 anyway).
// -------------------------------------------------------------------------
#define AB_EXT 391
#define AB_INT 196
#define AB_BAT 13
#define AB_PRE 8

__global__ __launch_bounds__(256) void aux_kernel(
    const int4* __restrict__ ei4, const int4* __restrict__ iei4,
    const int* __restrict__ batch,
    const float* __restrict__ wu_e1, const float* __restrict__ wu_e2,
    const float* __restrict__ wu_i1, const float* __restrict__ wu_i2,
    unsigned int* __restrict__ degb_ext, unsigned int* __restrict__ degb_int,
    int* __restrict__ cnt,
    unsigned short* __restrict__ WB, float* __restrict__ wcolp, int ncopy)
{
  __shared__ float WS[64 * 129];
  __shared__ int   hb[64];
  const int b = blockIdx.x, t = threadIdx.x;
  const int cp = b & (ncopy - 1);

  if (b < AB_EXT) {
    const int base = b * 512 + t;
    #pragma unroll
    for (int u = 0; u < 2; ++u) {
      const int i = base + u * 256;
      if (i < NE / 4) {
        const int4 v = ei4[i];
        atomicAdd(&degb_ext[v.x >> 2], 1u << (8 * (v.x & 3)));
        atomicAdd(&degb_ext[v.y >> 2], 1u << (8 * (v.y & 3)));
        atomicAdd(&degb_ext[v.z >> 2], 1u << (8 * (v.z & 3)));
        atomicAdd(&degb_ext[v.w >> 2], 1u << (8 * (v.w & 3)));
      }
    }
  } else if (b < AB_EXT + AB_INT) {
    const int base = (b - AB_EXT) * 512 + t;
    #pragma unroll
    for (int u = 0; u < 2; ++u) {
      const int i = base + u * 256;
      if (i < NEI / 4) {
        const int4 v = iei4[i];
        atomicAdd(&degb_int[v.x >> 2], 1u << (8 * (v.x & 3)));
        atomicAdd(&degb_int[v.y >> 2], 1u << (8 * (v.y & 3)));
        atomicAdd(&degb_int[v.z >> 2], 1u << (8 * (v.z & 3)));
        atomicAdd(&degb_int[v.w >> 2], 1u << (8 * (v.w & 3)));
      }
    }
  } else if (b < AB_EXT + AB_INT + AB_BAT) {
    if (t < 64) hb[t] = 0;
    __syncthreads();
    const int base = (b - AB_EXT - AB_INT) * 4096 + t;
    for (int u = 0; u < 16; ++u) {
      const int i = base + u * 256;
      if (i < NN) atomicAdd(&hb[batch[i]], 1);
    }
    __syncthreads();
    if (t < 64 && hb[t]) atomicAdd(&cnt[cp * CNT_STRIDE + t], hb[t]);
  } else {
    const int pb = b - AB_EXT - AB_INT - AB_BAT;   // 0..7
    const int c  = pb >> 1;                         // conv 0..3
    const int h  = pb & 1;                          // row half
    const float* wu = (c == 0) ? wu_e1 : (c == 1) ? wu_e2 : (c == 2) ? wu_i1 : wu_i2;
    for (int idx = t; idx < 64 * 129; idx += 256)
      WS[idx] = wu[(size_t)h * 64 * 129 + idx];
    __syncthreads();
    const int lane = t & 63, u = t >> 6;
    const int n = lane & 15, quad = lane >> 4;
    const int ct = 4 * h + u;
    unsigned short* wb = WB + c * 32768;
    #pragma unroll
    for (int kc = 0; kc < 4; ++kc) {
      const int k0 = kc * 32 + quad * 8;
      const float* src = &WS[(u * 16 + n) * 129 + k0];
      short8 hi, lo;
      #pragma unroll
      for (int e = 0; e < 8; ++e) {
        const float v = src[e];
        const unsigned short hh = bf16h(v);
        hi[e] = (short)hh;
        lo[e] = (short)bf16h(v - bf16tof(hh));
      }
      const int fbase = ((ct * 4 + kc) * 2) * 512 + lane * 8;
      *(short8*)&wb[fbase]       = hi;
      *(short8*)&wb[fbase + 512] = lo;
    }
    if (t < 64) wcolp[c * 128 + h * 64 + t] = WS[t * 129 + 128];
  }
}

// -------------------------------------------------------------------------
// Fused conv chain — R18 geometry (PASSED, occupancy lever confirmed):
// 32-row/256-thread/4-wave blocks, __launch_bounds__(256,4), chain-pass-
// split conv with per-kc ping-pong B.  R19 delta: deg read directly from
// the packed byte arrays (merge kernel deleted).
// -------------------------------------------------------------------------
#define ROWS 32

__global__ __launch_bounds__(256, 4) void conv_mfma_kernel(
    const float* __restrict__ x,
    const unsigned int* __restrict__ degb_ext,
    const unsigned int* __restrict__ degb_int,
    const int* __restrict__ batch,
    const unsigned short* __restrict__ WB, const float* __restrict__ wcolp,
    const float* __restrict__ bu_e1, const float* __restrict__ bu_e2,
    const float* __restrict__ bu_i1, const float* __restrict__ bu_i2,
    float* __restrict__ ez_sum, float* __restrict__ iz_sum, int ncopy)
{
  __shared__ unsigned short XT[2][4096];   // A fragments (bf16), 2 x 8 KB
  __shared__ float degsE[ROWS];
  __shared__ float degsI[ROWS];
  __shared__ int   bg[ROWS];
  __shared__ float redA[ROWS * 4];         // [row][wave]: s1e, then s2e
  __shared__ float redB[ROWS * 4];         // [row][wave]: s1i, then s2i

  const int tid  = threadIdx.x;
  const int lane = tid & 63;
  const int w    = tid >> 6;        // wave 0..3; owns ctA=w, ctB=w+4
  const int n    = lane & 15;
  const int q    = lane >> 4;
  const int mbase = blockIdx.x * ROWS;
  const int cp = blockIdx.x & (ncopy - 1);
  const int jA = w * 16 + n;
  const int jB = (w + 4) * 16 + n;

// Per-kc fragment quad for ONE conv index C: {ctA-hi, ctA-lo, ctB-hi, ctB-lo}
#define LOADP(C, KC, P) do {                                                  \
    const unsigned short* _p = WB + (C) * 32768 + (w * 4 + (KC)) * 1024 + lane * 8; \
    P[0] = *(const short8*)&_p[0];     P[1] = *(const short8*)&_p[512];       \
    P[2] = *(const short8*)&_p[16384]; P[3] = *(const short8*)&_p[16896];     \
  } while (0)

// One kc-step of a single-chain pass on XT[XB] into ACC[rt][s]
#define PSTEP(XB, KC, P, ACC) do {                                            \
    _Pragma("unroll")                                                          \
    for (int rt = 0; rt < 2; ++rt) {                                           \
      const short8 Ah = *(const short8*)&XT[XB][((rt * 4 + (KC)) * 64 + lane) * 8]; \
      f32x4 c0 = ACC[rt][0];                                                   \
      c0 = __builtin_amdgcn_mfma_f32_16x16x32_bf16(Ah, P[0], c0, 0, 0, 0);     \
      c0 = __builtin_amdgcn_mfma_f32_16x16x32_bf16(Ah, P[1], c0, 0, 0, 0);     \
      ACC[rt][0] = c0;                                                         \
      f32x4 c1 = ACC[rt][1];                                                   \
      c1 = __builtin_amdgcn_mfma_f32_16x16x32_bf16(Ah, P[2], c1, 0, 0, 0);     \
      c1 = __builtin_amdgcn_mfma_f32_16x16x32_bf16(Ah, P[3], c1, 0, 0, 0);     \
      ACC[rt][1] = c1;                                                         \
    }                                                                          \
  } while (0)

// Full 4-kc single-chain pass with ping-pong prefetch (Pa/Pb reused)
#define PASS(XB, C, ACC) do {                                                 \
    PSTEP(XB, 0, Pa, ACC);                                                    \
    LOADP(C, 2, Pa);                                                          \
    PSTEP(XB, 1, Pb, ACC);                                                    \
    LOADP(C, 3, Pb);                                                          \
    PSTEP(XB, 2, Pa, ACC);                                                    \
    PSTEP(XB, 3, Pb, ACC);                                                    \
  } while (0)

  // ---- early B prefetch for conv1-E pass (kc 0,1)
  short8 Pa[4], Pb[4];
  LOADP(0, 0, Pa);
  LOADP(0, 1, Pb);
  const float wcE1A = wcolp[0 * 128 + jA], wcE1B = wcolp[0 * 128 + jB];
  const float wcE2A = wcolp[1 * 128 + jA], wcE2B = wcolp[1 * 128 + jB];
  const float wcI1A = wcolp[2 * 128 + jA], wcI1B = wcolp[2 * 128 + jB];
  const float wcI2A = wcolp[3 * 128 + jA], wcI2B = wcolp[3 * 128 + jB];
  const float bE1A = bu_e1[jA], bE1B = bu_e1[jB];
  const float bE2A = bu_e2[jA], bE2B = bu_e2[jB];
  const float bI1A = bu_i1[jA], bI1B = bu_i1[jB];
  const float bI2A = bu_i2[jA], bI2B = bu_i2[jB];

  // ---- stage x -> bf16 A fragments in XT[0], octet-linear (conflict-free)
  #pragma unroll
  for (int u = 0; u < 2; ++u) {
    const int oct  = u * 256 + tid;          // 512 octets
    const int frag = oct >> 6, l = oct & 63;
    const int row  = (frag >> 2) * 16 + (l & 15);
    const int k0   = (frag & 3) * 32 + (l >> 4) * 8;
    const int node = mbase + row;
    float4 a = make_float4(0.f, 0.f, 0.f, 0.f), bb = a;
    if (node < NN) {
      const float* xr = x + (size_t)node * FD + k0;
      a  = *(const float4*)xr;
      bb = *(const float4*)(xr + 4);
    }
    S8 hi;
    hi.u[0] = pk_bf16(a.x, a.y);
    hi.u[1] = pk_bf16(a.z, a.w);
    hi.u[2] = pk_bf16(bb.x, bb.y);
    hi.u[3] = pk_bf16(bb.z, bb.w);
    *(short8*)&XT[0][oct * 8] = hi.s;
  }
  if (tid < ROWS) {
    const int node = mbase + tid;
    const bool v = node < NN;
    const int nc = v ? node : (NN - 1);
    const unsigned de = (degb_ext[nc >> 2] >> (8 * (nc & 3))) & 255u;
    const unsigned di = (degb_int[nc >> 2] >> (8 * (nc & 3))) & 255u;
    degsE[tid] = v ? (float)de : 0.f;
    degsI[tid] = v ? (float)di : 0.f;
    bg[tid]    = batch[nc];       // clamped: invalid rows inherit last graph
  }
  __syncthreads();   // ---- barrier 1: A fragments + degs + bg visible

  // ================= conv1: pass E, then pass I (ping-pong B) ============
  f32x4 aE[2][2], aI[2][2];
  #pragma unroll
  for (int rt = 0; rt < 2; ++rt)
    #pragma unroll
    for (int s = 0; s < 2; ++s) {
      aE[rt][s] = (f32x4){0.f, 0.f, 0.f, 0.f};
      aI[rt][s] = (f32x4){0.f, 0.f, 0.f, 0.f};
    }
  PASS(0, 0, aE);          // ext conv1
  LOADP(2, 0, Pa);
  LOADP(2, 1, Pb);
  PASS(0, 2, aI);          // int conv1

  // ---- epilogue1: E1 = exp(leaky(acc + b + deg*wc)), f32
  #pragma unroll
  for (int rt = 0; rt < 2; ++rt) {
    const float4 dE = *(const float4*)&degsE[rt * 16 + 4 * q];
    const float4 dI = *(const float4*)&degsI[rt * 16 + 4 * q];
    const float dEv[4] = {dE.x, dE.y, dE.z, dE.w};
    const float dIv[4] = {dI.x, dI.y, dI.z, dI.w};
    #pragma unroll
    for (int r = 0; r < 4; ++r) {
      float v;
      v = aE[rt][0][r] + bE1A + dEv[r] * wcE1A; v = fmaxf(v, 0.01f * v); aE[rt][0][r] = __expf(v);
      v = aE[rt][1][r] + bE1B + dEv[r] * wcE1B; v = fmaxf(v, 0.01f * v); aE[rt][1][r] = __expf(v);
      v = aI[rt][0][r] + bI1A + dIv[r] * wcI1A; v = fmaxf(v, 0.01f * v); aI[rt][0][r] = __expf(v);
      v = aI[rt][1][r] + bI1B + dIv[r] * wcI1B; v = fmaxf(v, 0.01f * v); aI[rt][1][r] = __expf(v);
    }
  }

  // ---- s1 partials: row-sum over this wave's 32 cols (ctA+ctB)
  #pragma unroll
  for (int rt = 0; rt < 2; ++rt) {
    #pragma unroll
    for (int r = 0; r < 4; ++r) {
      float te = aE[rt][0][r] + aE[rt][1][r];
      float ti = aI[rt][0][r] + aI[rt][1][r];
      te += __shfl_xor(te, 1); ti += __shfl_xor(ti, 1);
      te += __shfl_xor(te, 2); ti += __shfl_xor(ti, 2);
      te += __shfl_xor(te, 4); ti += __shfl_xor(ti, 4);
      te += __shfl_xor(te, 8); ti += __shfl_xor(ti, 8);
      if (n == 0) {
        redA[(rt * 16 + q * 4 + r) * 4 + w] = te;
        redB[(rt * 16 + q * 4 + r) * 4 + w] = ti;
      }
    }
  }

  // ---- pack E1 to bf16 pairs; prefetch conv2-ext B (kc 0,1)
  unsigned int pE[2][2][2], pI[2][2][2];
  #pragma unroll
  for (int rt = 0; rt < 2; ++rt)
    #pragma unroll
    for (int s = 0; s < 2; ++s) {
      pE[rt][s][0] = pk_bf16(aE[rt][s][0], aE[rt][s][1]);
      pE[rt][s][1] = pk_bf16(aE[rt][s][2], aE[rt][s][3]);
      pI[rt][s][0] = pk_bf16(aI[rt][s][0], aI[rt][s][1]);
      pI[rt][s][1] = pk_bf16(aI[rt][s][2], aI[rt][s][3]);
    }
  LOADP(1, 0, Pa);
  LOADP(1, 1, Pb);

  // ---- write E1e -> XT[1] in A-fragment order
  #pragma unroll
  for (int rt = 0; rt < 2; ++rt)
    #pragma unroll
    for (int s = 0; s < 2; ++s) {
      const int ct = w + s * 4;
      const int ib = ((rt * 4 + (ct >> 1)) * 64 + ((ct & 1) * 2 + (n >> 3)) * 16 + q * 4) * 8 + (n & 7);
      XT[1][ib]      = (unsigned short)(pE[rt][s][0] & 0xFFFFu);
      XT[1][ib + 8]  = (unsigned short)(pE[rt][s][0] >> 16);
      XT[1][ib + 16] = (unsigned short)(pE[rt][s][1] & 0xFFFFu);
      XT[1][ib + 24] = (unsigned short)(pE[rt][s][1] >> 16);
    }
  __syncthreads();   // ---- barrier 2: XT1 + s1 partials visible; XT0 reads done

  // ---- write E1i -> XT[0] (conv1 reads done)
  #pragma unroll
  for (int rt = 0; rt < 2; ++rt)
    #pragma unroll
    for (int s = 0; s < 2; ++s) {
      const int ct = w + s * 4;
      const int ib = ((rt * 4 + (ct >> 1)) * 64 + ((ct & 1) * 2 + (n >> 3)) * 16 + q * 4) * 8 + (n & 7);
      XT[0][ib]      = (unsigned short)(pI[rt][s][0] & 0xFFFFu);
      XT[0][ib + 8]  = (unsigned short)(pI[rt][s][0] >> 16);
      XT[0][ib + 16] = (unsigned short)(pI[rt][s][1] & 0xFFFFu);
      XT[0][ib + 24] = (unsigned short)(pI[rt][s][1] >> 16);
    }

  // ---- row-owned s1 inverses: lane ℓ&31 owns row ℓ&31
  float s1iE, s1iI;
  {
    const int rl = (lane & 31) * 4;
    const f32x4 a0 = *(const f32x4*)&redA[rl];
    s1iE = frcp((a0[0] + a0[1]) + (a0[2] + a0[3]));
    const f32x4 b0 = *(const f32x4*)&redB[rl];
    s1iI = frcp((b0[0] + b0[1]) + (b0[2] + b0[3]));
  }

  // ================= conv2-ext from XT[1] =================
  f32x4 cE[2][2], cI[2][2];
  #pragma unroll
  for (int rt = 0; rt < 2; ++rt)
    #pragma unroll
    for (int s = 0; s < 2; ++s) cE[rt][s] = (f32x4){0.f, 0.f, 0.f, 0.f};
  PASS(1, 1, cE);          // ext conv2 from XT1
  LOADP(3, 0, Pa);         // conv2-int prefetch (consumed after barrier 3)
  LOADP(3, 1, Pb);
  __syncthreads();   // ---- barrier 3: E1i visible; redA/redB s1-reads done

  // ================= conv2-int from XT[0] =================
  #pragma unroll
  for (int rt = 0; rt < 2; ++rt)
    #pragma unroll
    for (int s = 0; s < 2; ++s) cI[rt][s] = (f32x4){0.f, 0.f, 0.f, 0.f};
  PASS(0, 3, cI);          // int conv2 from XT0

  // ---- epilogue2: logits = U2*inv_s1 + b + deg*wc; E2 = exp(leaky(.));
  //      s2 partials -> redA/redB (safe after b3)
  #pragma unroll
  for (int rt = 0; rt < 2; ++rt) {
    const float4 dE = *(const float4*)&degsE[rt * 16 + 4 * q];
    const float4 dI = *(const float4*)&degsI[rt * 16 + 4 * q];
    const float dEv[4] = {dE.x, dE.y, dE.z, dE.w};
    const float dIv[4] = {dI.x, dI.y, dI.z, dI.w};
    #pragma unroll
    for (int r = 0; r < 4; ++r) {
      const int row = rt * 16 + q * 4 + r;
      const float i1e = __shfl(s1iE, row);
      const float i1i = __shfl(s1iI, row);
      float v;
      v = cE[rt][0][r] * i1e + bE2A + dEv[r] * wcE2A; v = fmaxf(v, 0.01f * v); cE[rt][0][r] = __expf(v);
      v = cE[rt][1][r] * i1e + bE2B + dEv[r] * wcE2B; v = fmaxf(v, 0.01f * v); cE[rt][1][r] = __expf(v);
      v = cI[rt][0][r] * i1i + bI2A + dIv[r] * wcI2A; v = fmaxf(v, 0.01f * v); cI[rt][0][r] = __expf(v);
      v = cI[rt][1][r] * i1i + bI2B + dIv[r] * wcI2B; v = fmaxf(v, 0.01f * v); cI[rt][1][r] = __expf(v);
    }
    #pragma unroll
    for (int r = 0; r < 4; ++r) {
      float te = cE[rt][0][r] + cE[rt][1][r];
      float ti = cI[rt][0][r] + cI[rt][1][r];
      te += __shfl_xor(te, 1); ti += __shfl_xor(ti, 1);
      te += __shfl_xor(te, 2); ti += __shfl_xor(ti, 2);
      te += __shfl_xor(te, 4); ti += __shfl_xor(ti, 4);
      te += __shfl_xor(te, 8); ti += __shfl_xor(ti, 8);
      if (n == 0) {
        redA[(rt * 16 + q * 4 + r) * 4 + w] = te;
        redB[(rt * 16 + q * 4 + r) * 4 + w] = ti;
      }
    }
  }
  __syncthreads();   // ---- barrier 4: s2 partials visible

  // ---- row-owned s2 inverses + normalize
  float s2iE, s2iI;
  {
    const int rl = (lane & 31) * 4;
    const f32x4 a0 = *(const f32x4*)&redA[rl];
    s2iE = frcp((a0[0] + a0[1]) + (a0[2] + a0[3]));
    const f32x4 b0 = *(const f32x4*)&redB[rl];
    s2iI = frcp((b0[0] + b0[1]) + (b0[2] + b0[3]));
  }
  #pragma unroll
  for (int rt = 0; rt < 2; ++rt) {
    #pragma unroll
    for (int r = 0; r < 4; ++r) {
      const int row = rt * 16 + q * 4 + r;
      const float i2e = __shfl(s2iE, row);
      const float i2i = __shfl(s2iI, row);
      cE[rt][0][r] *= i2e; cE[rt][1][r] *= i2e;
      cI[rt][0][r] *= i2i; cI[rt][1][r] *= i2i;
    }
  }

  // ---- scatter into XCD-private per-graph sums (masked per-graph reduce)
  {
    float* __restrict__ ezp = ez_sum + (size_t)cp * EZ_STRIDE;
    float* __restrict__ izp = iz_sum + (size_t)cp * EZ_STRIDE;

    if (mbase + ROWS - 1 >= NN) {   // zero out-of-range rows (last block)
      #pragma unroll
      for (int rt = 0; rt < 2; ++rt)
        #pragma unroll
        for (int r = 0; r < 4; ++r) {
          const int row = rt * 16 + q * 4 + r;
          if (mbase + row >= NN) {
            cE[rt][0][r] = 0.f; cE[rt][1][r] = 0.f;
            cI[rt][0][r] = 0.f; cI[rt][1][r] = 0.f;
          }
        }
    }

    const int g0 = bg[0], g1 = bg[ROWS - 1];
    for (int g = g0; g <= g1; ++g) {
      const bool one = (g0 == g1);
      float seA = 0.f, siA = 0.f, seB = 0.f, siB = 0.f;
      #pragma unroll
      for (int rt = 0; rt < 2; ++rt)
        #pragma unroll
        for (int r = 0; r < 4; ++r) {
          const int row = rt * 16 + q * 4 + r;
          const bool m = one || (bg[row] == g);
          seA += m ? cE[rt][0][r] : 0.f;
          seB += m ? cE[rt][1][r] : 0.f;
          siA += m ? cI[rt][0][r] : 0.f;
          siB += m ? cI[rt][1][r] : 0.f;
        }
      seA += __shfl_xor(seA, 16); siA += __shfl_xor(siA, 16);
      seB += __shfl_xor(seB, 16); siB += __shfl_xor(siB, 16);
      seA += __shfl_xor(seA, 32); siA += __shfl_xor(siA, 32);
      seB += __shfl_xor(seB, 32); siB += __shfl_xor(siB, 32);
      if (q == 0) {
        atomicAdd(&ezp[g * FD + jA], seA);
        atomicAdd(&ezp[g * FD + jB], seB);
        atomicAdd(&izp[g * FD + jA], siA);
        atomicAdd(&izp[g * FD + jB], siB);
      }
    }
  }
#undef LOADP
#undef PSTEP
#undef PASS
}

// -------------------------------------------------------------------------
// Final MLP: 64 blocks (one per graph) x 128 threads.  Sums ncopy
// XCD-private partials for z and cnt.
// -------------------------------------------------------------------------
__global__ __launch_bounds__(128) void fc_kernel(
    const float* __restrict__ ez_sum, const float* __restrict__ iz_sum,
    const int* __restrict__ cnt,
    const float* __restrict__ fc1_w, const float* __restrict__ fc1_b,
    const float* __restrict__ fc2_w, const float* __restrict__ fc2_b,
    float* __restrict__ out, int ncopy)
{
  __shared__ float z[256];
  __shared__ float red2[2];
  const int g = blockIdx.x, t = threadIdx.x;
  int cc = 0;
  float se = 0.f, si = 0.f;
  for (int c = 0; c < ncopy; ++c) {
    cc += cnt[c * CNT_STRIDE + g];
    se += ez_sum[(size_t)c * EZ_STRIDE + g * 128 + t];
    si += iz_sum[(size_t)c * EZ_STRIDE + g * 128 + t];
  }
  const float denom = fmaxf((float)cc, 1.0f);
  z[t]       = se / denom;
  z[128 + t] = si / denom;
  __syncthreads();

  const float* wr = fc1_w + (size_t)t * 256;
  float a = fc1_b[t];
  #pragma unroll 4
  for (int c = 0; c < 256; c += 4) {
    const float4 wv = *(const float4*)(wr + c);
    a += wv.x * z[c] + wv.y * z[c + 1] + wv.z * z[c + 2] + wv.w * z[c + 3];
  }
  a = fmaxf(a, 0.f) * fc2_w[t];
  a += __shfl_xor(a, 1);
  a += __shfl_xor(a, 2);
  a += __shfl_xor(a, 4);
  a += __shfl_xor(a, 8);
  a += __shfl_xor(a, 16);
  a += __shfl_xor(a, 32);
  if ((t & 63) == 0) red2[t >> 6] = a;
  __syncthreads();
  if (t == 0) out[g] = red2[0] + red2[1] + fc2_b[0];
}

// -------------------------------------------------------------------------
extern "C" void kernel_launch(void* const* d_in, const int* in_sizes, int n_in,
                              void* d_out, int out_size, void* d_ws, size_t ws_size,
                              hipStream_t stream) {
  const float* x     = (const float*)d_in[0];
  const int4*  ei4   = (const int4*) d_in[1];   // [2,E]: first E = sources
  const int4*  iei4  = (const int4*) d_in[3];
  const int*   batch = (const int*)  d_in[5];
  const float* wu_e1 = (const float*)d_in[8];
  const float* bu_e1 = (const float*)d_in[9];
  const float* wu_e2 = (const float*)d_in[12];
  const float* bu_e2 = (const float*)d_in[13];
  const float* wu_i1 = (const float*)d_in[16];
  const float* bu_i1 = (const float*)d_in[17];
  const float* wu_i2 = (const float*)d_in[20];
  const float* bu_i2 = (const float*)d_in[21];
  const float* fc1_w = (const float*)d_in[22];
  const float* fc1_b = (const float*)d_in[23];
  const float* fc2_w = (const float*)d_in[24];
  const float* fc2_b = (const float*)d_in[25];

  // Layout: [degb_ext][degb_int][ncopy x ez][ncopy x iz][ncopy x cnt]
  //         | (zeroed up to here) | [WB][wcolp]
  const size_t need8 = 2ull * (DEGB_WORDS * 4) + 8ull * (2 * 32768 + 256)
                     + 262144 + 2048;
  const int ncopy = (ws_size >= need8) ? 8 : 1;

  char* ws = (char*)d_ws;
  size_t off = 0;
  unsigned int* degb_ext = (unsigned int*)(ws + off); off += DEGB_WORDS * 4;
  unsigned int* degb_int = (unsigned int*)(ws + off); off += DEGB_WORDS * 4;
  float* ez      = (float*)(ws + off); off += (size_t)ncopy * 32768;
  float* iz      = (float*)(ws + off); off += (size_t)ncopy * 32768;
  int*   cnt     = (int*)(ws + off);  off += (size_t)ncopy * 256;
  const size_t zero_bytes = off;
  unsigned short* WB = (unsigned short*)(ws + off); off += 262144;
  float* wcolp   = (float*)(ws + off); off += 2048;

  hipMemsetAsync(d_ws, 0, zero_bytes, stream);

  aux_kernel<<<AB_EXT + AB_INT + AB_BAT + AB_PRE, 256, 0, stream>>>(
      ei4, iei4, batch, wu_e1, wu_e2, wu_i1, wu_i2,
      degb_ext, degb_int, cnt, WB, wcolp, ncopy);

  conv_mfma_kernel<<<dim3((NN + ROWS - 1) / ROWS), 256, 0, stream>>>(
      x, degb_ext, degb_int, batch, WB, wcolp,
      bu_e1, bu_e2, bu_i1, bu_i2, ez, iz, ncopy);

  fc_kernel<<<NG, 128, 0, stream>>>(ez, iz, cnt, fc1_w, fc1_b, fc2_w, fc2_b,
                                    (float*)d_out, ncopy);
}

// Round 12
// 180.005 us; speedup vs baseline: 1.2409x; 1.2409x over previous
//
#include <hip/hip_runtime.h>
#include <hip/hip_bf16.h>

// Problem constants
#define NN  50000   // nodes
#define FD  128     // features
#define NE  800000  // external edges
#define NEI 400000  // internal edges
#define NG  64      // graphs

// Strides (elements) for XCD-privatized output accumulators
#define EZ_STRIDE  8192      // floats (32768 B per copy)
#define CNT_STRIDE 64        // ints   (256 B per copy)
#define DEGB_WORDS 12544     // packed byte counters: 4 nodes/word, 50176 B

// Histogram partition (R20): per-block LDS byte-histograms, flushed with
// plain stores; merged by word-adds.  32 ext + 16 int blocks, 6250 int4
// edge-loads each (exact: 32*6250 = NE/4, 16*6250 = NEI/4).
#define HB_E 32
#define HB_I 16
#define HB_SLICE 6250

typedef short  short8 __attribute__((ext_vector_type(8)));
typedef float  f32x4  __attribute__((ext_vector_type(4)));

union S8 { short8 s; unsigned int u[4]; };

__device__ __forceinline__ unsigned short bf16h(float f) {
  unsigned int u = __float_as_uint(f);
  u += 0x7FFFu + ((u >> 16) & 1u);            // RNE
  return (unsigned short)(u >> 16);
}
__device__ __forceinline__ float bf16tof(unsigned short h) {
  return __uint_as_float(((unsigned int)h) << 16);
}
// packed 2xf32 -> 2xbf16 (v_cvt_pk_bf16_f32): a in low 16, b in high 16
__device__ __forceinline__ unsigned int pk_bf16(float a, float b) {
  __hip_bfloat162 h = __float22bfloat162_rn(make_float2(a, b));
  unsigned int u;
  __builtin_memcpy(&u, &h, 4);
  return u;
}
// fast reciprocal: v_rcp_f32 (~1 ulp) — tolerance is 4.2e-5, plenty of slack
__device__ __forceinline__ float frcp(float x) { return __builtin_amdgcn_rcpf(x); }

// -------------------------------------------------------------------------
// ONE aux dispatch.  R20: edge-degree histogram via LDS-PRIVATIZED packed
// byte counters (full 50K-node range = 50 KB LDS per block), flushed with
// PLAIN coalesced stores to per-block partials.  Rationale: R19 proved aux
// is atomic-OP-COUNT bound (WRITE_SIZE == 1.2M ops x 32B granule regardless
// of footprint; memory-side RMW never merges).  This path issues ~0 global
// atomics for the histogram.  Per-block byte overflow impossible (~9.4K
// samples over 50K nodes -> max per-node count ~8 << 255).
// Blocks: [0,32) ext-hist, [32,48) int-hist, [48,61) batch, [61,69) W-prep.
// -------------------------------------------------------------------------
#define AB_BAT 13
#define AB_PRE 8

__global__ __launch_bounds__(256) void aux_kernel(
    const int4* __restrict__ ei4, const int4* __restrict__ iei4,
    const int* __restrict__ batch,
    const float* __restrict__ wu_e1, const float* __restrict__ wu_e2,
    const float* __restrict__ wu_i1, const float* __restrict__ wu_i2,
    unsigned int* __restrict__ degp,     // [HB_E ext copies][HB_I int copies]
    int* __restrict__ cnt,
    unsigned short* __restrict__ WB, float* __restrict__ wcolp, int ncopy)
{
  // 50,176 B overlay: histogram H (hist blocks) aliases WS (W-prep blocks)
  __shared__ __align__(16) unsigned char SM[DEGB_WORDS * 4];
  __shared__ int hb[64];
  unsigned int* H  = (unsigned int*)SM;
  float*        WS = (float*)SM;            // 33,024 B used by W-prep
  const int b = blockIdx.x, t = threadIdx.x;

  if (b < HB_E + HB_I) {
    // ---- LDS byte-histogram over the full node range
    for (int i = t; i < DEGB_WORDS; i += 256) H[i] = 0;
    __syncthreads();
    if (b < HB_E) {
      const int beg = b * HB_SLICE;
      const int end = min(beg + HB_SLICE, NE / 4);
      for (int i = beg + t; i < end; i += 256) {
        const int4 v = ei4[i];
        atomicAdd(&H[v.x >> 2], 1u << (8 * (v.x & 3)));
        atomicAdd(&H[v.y >> 2], 1u << (8 * (v.y & 3)));
        atomicAdd(&H[v.z >> 2], 1u << (8 * (v.z & 3)));
        atomicAdd(&H[v.w >> 2], 1u << (8 * (v.w & 3)));
      }
    } else {
      const int beg = (b - HB_E) * HB_SLICE;
      const int end = min(beg + HB_SLICE, NEI / 4);
      for (int i = beg + t; i < end; i += 256) {
        const int4 v = iei4[i];
        atomicAdd(&H[v.x >> 2], 1u << (8 * (v.x & 3)));
        atomicAdd(&H[v.y >> 2], 1u << (8 * (v.y & 3)));
        atomicAdd(&H[v.z >> 2], 1u << (8 * (v.z & 3)));
        atomicAdd(&H[v.w >> 2], 1u << (8 * (v.w & 3)));
      }
    }
    __syncthreads();
    // ---- flush: plain coalesced stores (NO global atomics)
    unsigned int* dst = degp + (size_t)b * DEGB_WORDS;
    for (int i = t; i < DEGB_WORDS; i += 256) dst[i] = H[i];
  } else if (b < HB_E + HB_I + AB_BAT) {
    const int cp = b & (ncopy - 1);
    if (t < 64) hb[t] = 0;
    __syncthreads();
    const int base = (b - HB_E - HB_I) * 4096 + t;
    for (int u = 0; u < 16; ++u) {
      const int i = base + u * 256;
      if (i < NN) atomicAdd(&hb[batch[i]], 1);
    }
    __syncthreads();
    if (t < 64 && hb[t]) atomicAdd(&cnt[cp * CNT_STRIDE + t], hb[t]);
  } else {
    const int pb = b - HB_E - HB_I - AB_BAT;        // 0..7
    const int c  = pb >> 1;                          // conv 0..3
    const int h  = pb & 1;                           // row half
    const float* wu = (c == 0) ? wu_e1 : (c == 1) ? wu_e2 : (c == 2) ? wu_i1 : wu_i2;
    for (int idx = t; idx < 64 * 129; idx += 256)
      WS[idx] = wu[(size_t)h * 64 * 129 + idx];
    __syncthreads();
    const int lane = t & 63, u = t >> 6;
    const int n = lane & 15, quad = lane >> 4;
    const int ct = 4 * h + u;
    unsigned short* wb = WB + c * 32768;
    #pragma unroll
    for (int kc = 0; kc < 4; ++kc) {
      const int k0 = kc * 32 + quad * 8;
      const float* src = &WS[(u * 16 + n) * 129 + k0];
      short8 hi, lo;
      #pragma unroll
      for (int e = 0; e < 8; ++e) {
        const float v = src[e];
        const unsigned short hh = bf16h(v);
        hi[e] = (short)hh;
        lo[e] = (short)bf16h(v - bf16tof(hh));
      }
      const int fbase = ((ct * 4 + kc) * 2) * 512 + lane * 8;
      *(short8*)&wb[fbase]       = hi;
      *(short8*)&wb[fbase + 512] = lo;
    }
    if (t < 64) wcolp[c * 128 + h * 64 + t] = WS[t * 129 + 128];
  }
}

// -------------------------------------------------------------------------
// Merge the per-block packed partials into degb = [ext 12544 | int 12544].
// Packed word-adds are carry-safe: per-byte totals <= max degree ~45 << 255.
// Coalesced column reads; ~2.4 MB total traffic.
// -------------------------------------------------------------------------
__global__ __launch_bounds__(256) void merge_deg_kernel(
    const unsigned int* __restrict__ degp, unsigned int* __restrict__ degb)
{
  const int w = blockIdx.x * 256 + threadIdx.x;
  if (w < DEGB_WORDS) {
    unsigned s = 0;
    #pragma unroll 4
    for (int c = 0; c < HB_E; ++c) s += degp[(size_t)c * DEGB_WORDS + w];
    degb[w] = s;
  } else if (w < 2 * DEGB_WORDS) {
    const int ww = w - DEGB_WORDS;
    unsigned s = 0;
    #pragma unroll 4
    for (int c = 0; c < HB_I; ++c) s += degp[(size_t)(HB_E + c) * DEGB_WORDS + ww];
    degb[w] = s;
  }
}

// -------------------------------------------------------------------------
// Fused conv chain — R18/R19 geometry (PASSED): 32-row/256-thread/4-wave
// blocks, __launch_bounds__(256,4), chain-pass-split conv with per-kc
// ping-pong B.  Reads packed byte degree counters (unchanged from R19).
// -------------------------------------------------------------------------
#define ROWS 32

__global__ __launch_bounds__(256, 4) void conv_mfma_kernel(
    const float* __restrict__ x,
    const unsigned int* __restrict__ degb_ext,
    const unsigned int* __restrict__ degb_int,
    const int* __restrict__ batch,
    const unsigned short* __restrict__ WB, const float* __restrict__ wcolp,
    const float* __restrict__ bu_e1, const float* __restrict__ bu_e2,
    const float* __restrict__ bu_i1, const float* __restrict__ bu_i2,
    float* __restrict__ ez_sum, float* __restrict__ iz_sum, int ncopy)
{
  __shared__ unsigned short XT[2][4096];   // A fragments (bf16), 2 x 8 KB
  __shared__ float degsE[ROWS];
  __shared__ float degsI[ROWS];
  __shared__ int   bg[ROWS];
  __shared__ float redA[ROWS * 4];         // [row][wave]: s1e, then s2e
  __shared__ float redB[ROWS * 4];         // [row][wave]: s1i, then s2i

  const int tid  = threadIdx.x;
  const int lane = tid & 63;
  const int w    = tid >> 6;        // wave 0..3; owns ctA=w, ctB=w+4
  const int n    = lane & 15;
  const int q    = lane >> 4;
  const int mbase = blockIdx.x * ROWS;
  const int cp = blockIdx.x & (ncopy - 1);
  const int jA = w * 16 + n;
  const int jB = (w + 4) * 16 + n;

// Per-kc fragment quad for ONE conv index C: {ctA-hi, ctA-lo, ctB-hi, ctB-lo}
#define LOADP(C, KC, P) do {                                                  \
    const unsigned short* _p = WB + (C) * 32768 + (w * 4 + (KC)) * 1024 + lane * 8; \
    P[0] = *(const short8*)&_p[0];     P[1] = *(const short8*)&_p[512];       \
    P[2] = *(const short8*)&_p[16384]; P[3] = *(const short8*)&_p[16896];     \
  } while (0)

// One kc-step of a single-chain pass on XT[XB] into ACC[rt][s]
#define PSTEP(XB, KC, P, ACC) do {                                            \
    _Pragma("unroll")                                                          \
    for (int rt = 0; rt < 2; ++rt) {                                           \
      const short8 Ah = *(const short8*)&XT[XB][((rt * 4 + (KC)) * 64 + lane) * 8]; \
      f32x4 c0 = ACC[rt][0];                                                   \
      c0 = __builtin_amdgcn_mfma_f32_16x16x32_bf16(Ah, P[0], c0, 0, 0, 0);     \
      c0 = __builtin_amdgcn_mfma_f32_16x16x32_bf16(Ah, P[1], c0, 0, 0, 0);     \
      ACC[rt][0] = c0;                                                         \
      f32x4 c1 = ACC[rt][1];                                                   \
      c1 = __builtin_amdgcn_mfma_f32_16x16x32_bf16(Ah, P[2], c1, 0, 0, 0);     \
      c1 = __builtin_amdgcn_mfma_f32_16x16x32_bf16(Ah, P[3], c1, 0, 0, 0);     \
      ACC[rt][1] = c1;                                                         \
    }                                                                          \
  } while (0)

// Full 4-kc single-chain pass with ping-pong prefetch (Pa/Pb reused)
#define PASS(XB, C, ACC) do {                                                 \
    PSTEP(XB, 0, Pa, ACC);                                                    \
    LOADP(C, 2, Pa);                                                          \
    PSTEP(XB, 1, Pb, ACC);                                                    \
    LOADP(C, 3, Pb);                                                          \
    PSTEP(XB, 2, Pa, ACC);                                                    \
    PSTEP(XB, 3, Pb, ACC);                                                    \
  } while (0)

  // ---- early B prefetch for conv1-E pass (kc 0,1)
  short8 Pa[4], Pb[4];
  LOADP(0, 0, Pa);
  LOADP(0, 1, Pb);
  const float wcE1A = wcolp[0 * 128 + jA], wcE1B = wcolp[0 * 128 + jB];
  const float wcE2A = wcolp[1 * 128 + jA], wcE2B = wcolp[1 * 128 + jB];
  const float wcI1A = wcolp[2 * 128 + jA], wcI1B = wcolp[2 * 128 + jB];
  const float wcI2A = wcolp[3 * 128 + jA], wcI2B = wcolp[3 * 128 + jB];
  const float bE1A = bu_e1[jA], bE1B = bu_e1[jB];
  const float bE2A = bu_e2[jA], bE2B = bu_e2[jB];
  const float bI1A = bu_i1[jA], bI1B = bu_i1[jB];
  const float bI2A = bu_i2[jA], bI2B = bu_i2[jB];

  // ---- stage x -> bf16 A fragments in XT[0], octet-linear (conflict-free)
  #pragma unroll
  for (int u = 0; u < 2; ++u) {
    const int oct  = u * 256 + tid;          // 512 octets
    const int frag = oct >> 6, l = oct & 63;
    const int row  = (frag >> 2) * 16 + (l & 15);
    const int k0   = (frag & 3) * 32 + (l >> 4) * 8;
    const int node = mbase + row;
    float4 a = make_float4(0.f, 0.f, 0.f, 0.f), bb = a;
    if (node < NN) {
      const float* xr = x + (size_t)node * FD + k0;
      a  = *(const float4*)xr;
      bb = *(const float4*)(xr + 4);
    }
    S8 hi;
    hi.u[0] = pk_bf16(a.x, a.y);
    hi.u[1] = pk_bf16(a.z, a.w);
    hi.u[2] = pk_bf16(bb.x, bb.y);
    hi.u[3] = pk_bf16(bb.z, bb.w);
    *(short8*)&XT[0][oct * 8] = hi.s;
  }
  if (tid < ROWS) {
    const int node = mbase + tid;
    const bool v = node < NN;
    const int nc = v ? node : (NN - 1);
    const unsigned de = (degb_ext[nc >> 2] >> (8 * (nc & 3))) & 255u;
    const unsigned di = (degb_int[nc >> 2] >> (8 * (nc & 3))) & 255u;
    degsE[tid] = v ? (float)de : 0.f;
    degsI[tid] = v ? (float)di : 0.f;
    bg[tid]    = batch[nc];       // clamped: invalid rows inherit last graph
  }
  __syncthreads();   // ---- barrier 1: A fragments + degs + bg visible

  // ================= conv1: pass E, then pass I (ping-pong B) ============
  f32x4 aE[2][2], aI[2][2];
  #pragma unroll
  for (int rt = 0; rt < 2; ++rt)
    #pragma unroll
    for (int s = 0; s < 2; ++s) {
      aE[rt][s] = (f32x4){0.f, 0.f, 0.f, 0.f};
      aI[rt][s] = (f32x4){0.f, 0.f, 0.f, 0.f};
    }
  PASS(0, 0, aE);          // ext conv1
  LOADP(2, 0, Pa);
  LOADP(2, 1, Pb);
  PASS(0, 2, aI);          // int conv1

  // ---- epilogue1: E1 = exp(leaky(acc + b + deg*wc)), f32
  #pragma unroll
  for (int rt = 0; rt < 2; ++rt) {
    const float4 dE = *(const float4*)&degsE[rt * 16 + 4 * q];
    const float4 dI = *(const float4*)&degsI[rt * 16 + 4 * q];
    const float dEv[4] = {dE.x, dE.y, dE.z, dE.w};
    const float dIv[4] = {dI.x, dI.y, dI.z, dI.w};
    #pragma unroll
    for (int r = 0; r < 4; ++r) {
      float v;
      v = aE[rt][0][r] + bE1A + dEv[r] * wcE1A; v = fmaxf(v, 0.01f * v); aE[rt][0][r] = __expf(v);
      v = aE[rt][1][r] + bE1B + dEv[r] * wcE1B; v = fmaxf(v, 0.01f * v); aE[rt][1][r] = __expf(v);
      v = aI[rt][0][r] + bI1A + dIv[r] * wcI1A; v = fmaxf(v, 0.01f * v); aI[rt][0][r] = __expf(v);
      v = aI[rt][1][r] + bI1B + dIv[r] * wcI1B; v = fmaxf(v, 0.01f * v); aI[rt][1][r] = __expf(v);
    }
  }

  // ---- s1 partials: row-sum over this wave's 32 cols (ctA+ctB)
  #pragma unroll
  for (int rt = 0; rt < 2; ++rt) {
    #pragma unroll
    for (int r = 0; r < 4; ++r) {
      float te = aE[rt][0][r] + aE[rt][1][r];
      float ti = aI[rt][0][r] + aI[rt][1][r];
      te += __shfl_xor(te, 1); ti += __shfl_xor(ti, 1);
      te += __shfl_xor(te, 2); ti += __shfl_xor(ti, 2);
      te += __shfl_xor(te, 4); ti += __shfl_xor(ti, 4);
      te += __shfl_xor(te, 8); ti += __shfl_xor(ti, 8);
      if (n == 0) {
        redA[(rt * 16 + q * 4 + r) * 4 + w] = te;
        redB[(rt * 16 + q * 4 + r) * 4 + w] = ti;
      }
    }
  }

  // ---- pack E1 to bf16 pairs; prefetch conv2-ext B (kc 0,1)
  unsigned int pE[2][2][2], pI[2][2][2];
  #pragma unroll
  for (int rt = 0; rt < 2; ++rt)
    #pragma unroll
    for (int s = 0; s < 2; ++s) {
      pE[rt][s][0] = pk_bf16(aE[rt][s][0], aE[rt][s][1]);
      pE[rt][s][1] = pk_bf16(aE[rt][s][2], aE[rt][s][3]);
      pI[rt][s][0] = pk_bf16(aI[rt][s][0], aI[rt][s][1]);
      pI[rt][s][1] = pk_bf16(aI[rt][s][2], aI[rt][s][3]);
    }
  LOADP(1, 0, Pa);
  LOADP(1, 1, Pb);

  // ---- write E1e -> XT[1] in A-fragment order
  #pragma unroll
  for (int rt = 0; rt < 2; ++rt)
    #pragma unroll
    for (int s = 0; s < 2; ++s) {
      const int ct = w + s * 4;
      const int ib = ((rt * 4 + (ct >> 1)) * 64 + ((ct & 1) * 2 + (n >> 3)) * 16 + q * 4) * 8 + (n & 7);
      XT[1][ib]      = (unsigned short)(pE[rt][s][0] & 0xFFFFu);
      XT[1][ib + 8]  = (unsigned short)(pE[rt][s][0] >> 16);
      XT[1][ib + 16] = (unsigned short)(pE[rt][s][1] & 0xFFFFu);
      XT[1][ib + 24] = (unsigned short)(pE[rt][s][1] >> 16);
    }
  __syncthreads();   // ---- barrier 2: XT1 + s1 partials visible; XT0 reads done

  // ---- write E1i -> XT[0] (conv1 reads done)
  #pragma unroll
  for (int rt = 0; rt < 2; ++rt)
    #pragma unroll
    for (int s = 0; s < 2; ++s) {
      const int ct = w + s * 4;
      const int ib = ((rt * 4 + (ct >> 1)) * 64 + ((ct & 1) * 2 + (n >> 3)) * 16 + q * 4) * 8 + (n & 7);
      XT[0][ib]      = (unsigned short)(pI[rt][s][0] & 0xFFFFu);
      XT[0][ib + 8]  = (unsigned short)(pI[rt][s][0] >> 16);
      XT[0][ib + 16] = (unsigned short)(pI[rt][s][1] & 0xFFFFu);
      XT[0][ib + 24] = (unsigned short)(pI[rt][s][1] >> 16);
    }

  // ---- row-owned s1 inverses: lane ℓ&31 owns row ℓ&31
  float s1iE, s1iI;
  {
    const int rl = (lane & 31) * 4;
    const f32x4 a0 = *(const f32x4*)&redA[rl];
    s1iE = frcp((a0[0] + a0[1]) + (a0[2] + a0[3]));
    const f32x4 b0 = *(const f32x4*)&redB[rl];
    s1iI = frcp((b0[0] + b0[1]) + (b0[2] + b0[3]));
  }

  // ================= conv2-ext from XT[1] =================
  f32x4 cE[2][2], cI[2][2];
  #pragma unroll
  for (int rt = 0; rt < 2; ++rt)
    #pragma unroll
    for (int s = 0; s < 2; ++s) cE[rt][s] = (f32x4){0.f, 0.f, 0.f, 0.f};
  PASS(1, 1, cE);          // ext conv2 from XT1
  LOADP(3, 0, Pa);         // conv2-int prefetch (consumed after barrier 3)
  LOADP(3, 1, Pb);
  __syncthreads();   // ---- barrier 3: E1i visible; redA/redB s1-reads done

  // ================= conv2-int from XT[0] =================
  #pragma unroll
  for (int rt = 0; rt < 2; ++rt)
    #pragma unroll
    for (int s = 0; s < 2; ++s) cI[rt][s] = (f32x4){0.f, 0.f, 0.f, 0.f};
  PASS(0, 3, cI);          // int conv2 from XT0

  // ---- epilogue2: logits = U2*inv_s1 + b + deg*wc; E2 = exp(leaky(.));
  //      s2 partials -> redA/redB (safe after b3)
  #pragma unroll
  for (int rt = 0; rt < 2; ++rt) {
    const float4 dE = *(const float4*)&degsE[rt * 16 + 4 * q];
    const float4 dI = *(const float4*)&degsI[rt * 16 + 4 * q];
    const float dEv[4] = {dE.x, dE.y, dE.z, dE.w};
    const float dIv[4] = {dI.x, dI.y, dI.z, dI.w};
    #pragma unroll
    for (int r = 0; r < 4; ++r) {
      const int row = rt * 16 + q * 4 + r;
      const float i1e = __shfl(s1iE, row);
      const float i1i = __shfl(s1iI, row);
      float v;
      v = cE[rt][0][r] * i1e + bE2A + dEv[r] * wcE2A; v = fmaxf(v, 0.01f * v); cE[rt][0][r] = __expf(v);
      v = cE[rt][1][r] * i1e + bE2B + dEv[r] * wcE2B; v = fmaxf(v, 0.01f * v); cE[rt][1][r] = __expf(v);
      v = cI[rt][0][r] * i1i + bI2A + dIv[r] * wcI2A; v = fmaxf(v, 0.01f * v); cI[rt][0][r] = __expf(v);
      v = cI[rt][1][r] * i1i + bI2B + dIv[r] * wcI2B; v = fmaxf(v, 0.01f * v); cI[rt][1][r] = __expf(v);
    }
    #pragma unroll
    for (int r = 0; r < 4; ++r) {
      float te = cE[rt][0][r] + cE[rt][1][r];
      float ti = cI[rt][0][r] + cI[rt][1][r];
      te += __shfl_xor(te, 1); ti += __shfl_xor(ti, 1);
      te += __shfl_xor(te, 2); ti += __shfl_xor(ti, 2);
      te += __shfl_xor(te, 4); ti += __shfl_xor(ti, 4);
      te += __shfl_xor(te, 8); ti += __shfl_xor(ti, 8);
      if (n == 0) {
        redA[(rt * 16 + q * 4 + r) * 4 + w] = te;
        redB[(rt * 16 + q * 4 + r) * 4 + w] = ti;
      }
    }
  }
  __syncthreads();   // ---- barrier 4: s2 partials visible

  // ---- row-owned s2 inverses + normalize
  float s2iE, s2iI;
  {
    const int rl = (lane & 31) * 4;
    const f32x4 a0 = *(const f32x4*)&redA[rl];
    s2iE = frcp((a0[0] + a0[1]) + (a0[2] + a0[3]));
    const f32x4 b0 = *(const f32x4*)&redB[rl];
    s2iI = frcp((b0[0] + b0[1]) + (b0[2] + b0[3]));
  }
  #pragma unroll
  for (int rt = 0; rt < 2; ++rt) {
    #pragma unroll
    for (int r = 0; r < 4; ++r) {
      const int row = rt * 16 + q * 4 + r;
      const float i2e = __shfl(s2iE, row);
      const float i2i = __shfl(s2iI, row);
      cE[rt][0][r] *= i2e; cE[rt][1][r] *= i2e;
      cI[rt][0][r] *= i2i; cI[rt][1][r] *= i2i;
    }
  }

  // ---- scatter into XCD-private per-graph sums (masked per-graph reduce)
  {
    float* __restrict__ ezp = ez_sum + (size_t)cp * EZ_STRIDE;
    float* __restrict__ izp = iz_sum + (size_t)cp * EZ_STRIDE;

    if (mbase + ROWS - 1 >= NN) {   // zero out-of-range rows (last block)
      #pragma unroll
      for (int rt = 0; rt < 2; ++rt)
        #pragma unroll
        for (int r = 0; r < 4; ++r) {
          const int row = rt * 16 + q * 4 + r;
          if (mbase + row >= NN) {
            cE[rt][0][r] = 0.f; cE[rt][1][r] = 0.f;
            cI[rt][0][r] = 0.f; cI[rt][1][r] = 0.f;
          }
        }
    }

    const int g0 = bg[0], g1 = bg[ROWS - 1];
    for (int g = g0; g <= g1; ++g) {
      const bool one = (g0 == g1);
      float seA = 0.f, siA = 0.f, seB = 0.f, siB = 0.f;
      #pragma unroll
      for (int rt = 0; rt < 2; ++rt)
        #pragma unroll
        for (int r = 0; r < 4; ++r) {
          const int row = rt * 16 + q * 4 + r;
          const bool m = one || (bg[row] == g);
          seA += m ? cE[rt][0][r] : 0.f;
          seB += m ? cE[rt][1][r] : 0.f;
          siA += m ? cI[rt][0][r] : 0.f;
          siB += m ? cI[rt][1][r] : 0.f;
        }
      seA += __shfl_xor(seA, 16); siA += __shfl_xor(siA, 16);
      seB += __shfl_xor(seB, 16); siB += __shfl_xor(siB, 16);
      seA += __shfl_xor(seA, 32); siA += __shfl_xor(siA, 32);
      seB += __shfl_xor(seB, 32); siB += __shfl_xor(siB, 32);
      if (q == 0) {
        atomicAdd(&ezp[g * FD + jA], seA);
        atomicAdd(&ezp[g * FD + jB], seB);
        atomicAdd(&izp[g * FD + jA], siA);
        atomicAdd(&izp[g * FD + jB], siB);
      }
    }
  }
#undef LOADP
#undef PSTEP
#undef PASS
}

// -------------------------------------------------------------------------
// Final MLP: 64 blocks (one per graph) x 128 threads.  Sums ncopy
// XCD-private partials for z and cnt.
// -------------------------------------------------------------------------
__global__ __launch_bounds__(128) void fc_kernel(
    const float* __restrict__ ez_sum, const float* __restrict__ iz_sum,
    const int* __restrict__ cnt,
    const float* __restrict__ fc1_w, const float* __restrict__ fc1_b,
    const float* __restrict__ fc2_w, const float* __restrict__ fc2_b,
    float* __restrict__ out, int ncopy)
{
  __shared__ float z[256];
  __shared__ float red2[2];
  const int g = blockIdx.x, t = threadIdx.x;
  int cc = 0;
  float se = 0.f, si = 0.f;
  for (int c = 0; c < ncopy; ++c) {
    cc += cnt[c * CNT_STRIDE + g];
    se += ez_sum[(size_t)c * EZ_STRIDE + g * 128 + t];
    si += iz_sum[(size_t)c * EZ_STRIDE + g * 128 + t];
  }
  const float denom = fmaxf((float)cc, 1.0f);
  z[t]       = se / denom;
  z[128 + t] = si / denom;
  __syncthreads();

  const float* wr = fc1_w + (size_t)t * 256;
  float a = fc1_b[t];
  #pragma unroll 4
  for (int c = 0; c < 256; c += 4) {
    const float4 wv = *(const float4*)(wr + c);
    a += wv.x * z[c] + wv.y * z[c + 1] + wv.z * z[c + 2] + wv.w * z[c + 3];
  }
  a = fmaxf(a, 0.f) * fc2_w[t];
  a += __shfl_xor(a, 1);
  a += __shfl_xor(a, 2);
  a += __shfl_xor(a, 4);
  a += __shfl_xor(a, 8);
  a += __shfl_xor(a, 16);
  a += __shfl_xor(a, 32);
  if ((t & 63) == 0) red2[t >> 6] = a;
  __syncthreads();
  if (t == 0) out[g] = red2[0] + red2[1] + fc2_b[0];
}

// -------------------------------------------------------------------------
extern "C" void kernel_launch(void* const* d_in, const int* in_sizes, int n_in,
                              void* d_out, int out_size, void* d_ws, size_t ws_size,
                              hipStream_t stream) {
  const float* x     = (const float*)d_in[0];
  const int4*  ei4   = (const int4*) d_in[1];   // [2,E]: first E = sources
  const int4*  iei4  = (const int4*) d_in[3];
  const int*   batch = (const int*)  d_in[5];
  const float* wu_e1 = (const float*)d_in[8];
  const float* bu_e1 = (const float*)d_in[9];
  const float* wu_e2 = (const float*)d_in[12];
  const float* bu_e2 = (const float*)d_in[13];
  const float* wu_i1 = (const float*)d_in[16];
  const float* bu_i1 = (const float*)d_in[17];
  const float* wu_i2 = (const float*)d_in[20];
  const float* bu_i2 = (const float*)d_in[21];
  const float* fc1_w = (const float*)d_in[22];
  const float* fc1_b = (const float*)d_in[23];
  const float* fc2_w = (const float*)d_in[24];
  const float* fc2_b = (const float*)d_in[25];

  // Layout: [ncopy x ez][ncopy x iz][ncopy x cnt] | zeroed |
  //         [degb 2x50176][WB][wcolp][degp (HB_E+HB_I) x 50176]
  // Total @ ncopy=8: 526,336 + 100,352 + 262,144 + 2,048 + 2,408,448
  //                = 3,299,328 B  (< 3,871,232 B proven available R11-R19)
  const size_t need8 = 8ull * (2 * 32768 + 256) + 2 * (DEGB_WORDS * 4)
                     + 262144 + 2048 + (size_t)(HB_E + HB_I) * DEGB_WORDS * 4;
  const int ncopy = (ws_size >= need8) ? 8 : 1;

  char* ws = (char*)d_ws;
  size_t off = 0;
  float* ez      = (float*)(ws + off); off += (size_t)ncopy * 32768;
  float* iz      = (float*)(ws + off); off += (size_t)ncopy * 32768;
  int*   cnt     = (int*)(ws + off);  off += (size_t)ncopy * 256;
  const size_t zero_bytes = off;
  unsigned int* degb = (unsigned int*)(ws + off); off += 2 * DEGB_WORDS * 4;
  unsigned short* WB = (unsigned short*)(ws + off); off += 262144;
  float* wcolp   = (float*)(ws + off); off += 2048;
  unsigned int* degp = (unsigned int*)(ws + off);
  off += (size_t)(HB_E + HB_I) * DEGB_WORDS * 4;

  hipMemsetAsync(d_ws, 0, zero_bytes, stream);

  aux_kernel<<<HB_E + HB_I + AB_BAT + AB_PRE, 256, 0, stream>>>(
      ei4, iei4, batch, wu_e1, wu_e2, wu_i1, wu_i2,
      degp, cnt, WB, wcolp, ncopy);

  merge_deg_kernel<<<(2 * DEGB_WORDS + 255) / 256, 256, 0, stream>>>(
      degp, degb);

  conv_mfma_kernel<<<dim3((NN + ROWS - 1) / ROWS), 256, 0, stream>>>(
      x, degb, degb + DEGB_WORDS, batch, WB, wcolp,
      bu_e1, bu_e2, bu_i1, bu_i2, ez, iz, ncopy);

  fc_kernel<<<NG, 128, 0, stream>>>(ez, iz, cnt, fc1_w, fc1_b, fc2_w, fc2_b,
                                    (float*)d_out, ncopy);
}

// Round 13
// 170.179 us; speedup vs baseline: 1.3126x; 1.0577x over previous
//
#include <hip/hip_runtime.h>
#include <hip/hip_bf16.h>

// Problem constants
#define NN  50000   // nodes
#define FD  128     // features
#define NE  800000  // external edges
#define NEI 400000  // internal edges
#define NG  64      // graphs

// Strides (elements) for XCD-privatized output accumulators
#define EZ_STRIDE  8192      // floats (32768 B per copy)
#define CNT_SLOTS  13        // per-block batch-hist partials (plain stores)
#define DEGB_WORDS 12544     // packed byte counters: 4 nodes/word, 50176 B

// Histogram partition (R20, proven): per-block LDS byte-histograms flushed
// with plain stores.  32 ext + 16 int blocks, 6250 int4 edge-loads each.
#define HB_E 32
#define HB_I 16
#define HB_SLICE 6250

#define AB_BAT 13
#define AB_PRE 8
#define AB_ZERO 8

typedef short  short8 __attribute__((ext_vector_type(8)));
typedef float  f32x4  __attribute__((ext_vector_type(4)));

union S8 { short8 s; unsigned int u[4]; };

__device__ __forceinline__ unsigned short bf16h(float f) {
  unsigned int u = __float_as_uint(f);
  u += 0x7FFFu + ((u >> 16) & 1u);            // RNE
  return (unsigned short)(u >> 16);
}
__device__ __forceinline__ float bf16tof(unsigned short h) {
  return __uint_as_float(((unsigned int)h) << 16);
}
// packed 2xf32 -> 2xbf16 (v_cvt_pk_bf16_f32): a in low 16, b in high 16
__device__ __forceinline__ unsigned int pk_bf16(float a, float b) {
  __hip_bfloat162 h = __float22bfloat162_rn(make_float2(a, b));
  unsigned int u;
  __builtin_memcpy(&u, &h, 4);
  return u;
}
// fast reciprocal: v_rcp_f32 (~1 ulp) — tolerance is 4.2e-5, plenty of slack
__device__ __forceinline__ float frcp(float x) { return __builtin_amdgcn_rcpf(x); }

// -------------------------------------------------------------------------
// ONE aux dispatch (R21): LDS-privatized edge histograms (R20, proven) +
// batch partials as PLAIN per-block stores (no atomics -> no pre-zero) +
// ez/iz zeroing blocks (replaces hipMemsetAsync entirely).
// Blocks: [0,32) ext-hist, [32,48) int-hist, [48,61) batch, [61,69) W-prep,
//         [69,77) zero ez/iz.
// Every workspace region is fully WRITTEN each launch (harness-poison safe).
// -------------------------------------------------------------------------
__global__ __launch_bounds__(256) void aux_kernel(
    const int4* __restrict__ ei4, const int4* __restrict__ iei4,
    const int* __restrict__ batch,
    const float* __restrict__ wu_e1, const float* __restrict__ wu_e2,
    const float* __restrict__ wu_i1, const float* __restrict__ wu_i2,
    unsigned int* __restrict__ degp,     // [HB_E ext | HB_I int] partials
    int* __restrict__ cnt,               // CNT_SLOTS x 64 plain partials
    unsigned short* __restrict__ WB, float* __restrict__ wcolp,
    int4* __restrict__ zbuf, int zquads)
{
  // 50,176 B overlay: histogram H (hist blocks) aliases WS (W-prep blocks)
  __shared__ __align__(16) unsigned char SM[DEGB_WORDS * 4];
  __shared__ int hb[64];
  unsigned int* H  = (unsigned int*)SM;
  float*        WS = (float*)SM;            // 33,024 B used by W-prep
  const int b = blockIdx.x, t = threadIdx.x;

  if (b < HB_E + HB_I) {
    // ---- LDS byte-histogram over the full node range
    for (int i = t; i < DEGB_WORDS; i += 256) H[i] = 0;
    __syncthreads();
    if (b < HB_E) {
      const int beg = b * HB_SLICE;
      const int end = min(beg + HB_SLICE, NE / 4);
      for (int i = beg + t; i < end; i += 256) {
        const int4 v = ei4[i];
        atomicAdd(&H[v.x >> 2], 1u << (8 * (v.x & 3)));
        atomicAdd(&H[v.y >> 2], 1u << (8 * (v.y & 3)));
        atomicAdd(&H[v.z >> 2], 1u << (8 * (v.z & 3)));
        atomicAdd(&H[v.w >> 2], 1u << (8 * (v.w & 3)));
      }
    } else {
      const int beg = (b - HB_E) * HB_SLICE;
      const int end = min(beg + HB_SLICE, NEI / 4);
      for (int i = beg + t; i < end; i += 256) {
        const int4 v = iei4[i];
        atomicAdd(&H[v.x >> 2], 1u << (8 * (v.x & 3)));
        atomicAdd(&H[v.y >> 2], 1u << (8 * (v.y & 3)));
        atomicAdd(&H[v.z >> 2], 1u << (8 * (v.z & 3)));
        atomicAdd(&H[v.w >> 2], 1u << (8 * (v.w & 3)));
      }
    }
    __syncthreads();
    // ---- flush: plain coalesced stores (NO global atomics)
    unsigned int* dst = degp + (size_t)b * DEGB_WORDS;
    for (int i = t; i < DEGB_WORDS; i += 256) dst[i] = H[i];
  } else if (b < HB_E + HB_I + AB_BAT) {
    const int ib = b - HB_E - HB_I;            // 0..12
    if (t < 64) hb[t] = 0;
    __syncthreads();
    const int base = ib * 4096 + t;
    for (int u = 0; u < 16; ++u) {
      const int i = base + u * 256;
      if (i < NN) atomicAdd(&hb[batch[i]], 1);
    }
    __syncthreads();
    if (t < 64) cnt[ib * 64 + t] = hb[t];      // plain store
  } else if (b < HB_E + HB_I + AB_BAT + AB_PRE) {
    const int pb = b - HB_E - HB_I - AB_BAT;   // 0..7
    const int c  = pb >> 1;                     // conv 0..3
    const int h  = pb & 1;                      // row half
    const float* wu = (c == 0) ? wu_e1 : (c == 1) ? wu_e2 : (c == 2) ? wu_i1 : wu_i2;
    for (int idx = t; idx < 64 * 129; idx += 256)
      WS[idx] = wu[(size_t)h * 64 * 129 + idx];
    __syncthreads();
    const int lane = t & 63, u = t >> 6;
    const int n = lane & 15, quad = lane >> 4;
    const int ct = 4 * h + u;
    unsigned short* wb = WB + c * 32768;
    #pragma unroll
    for (int kc = 0; kc < 4; ++kc) {
      const int k0 = kc * 32 + quad * 8;
      const float* src = &WS[(u * 16 + n) * 129 + k0];
      short8 hi, lo;
      #pragma unroll
      for (int e = 0; e < 8; ++e) {
        const float v = src[e];
        const unsigned short hh = bf16h(v);
        hi[e] = (short)hh;
        lo[e] = (short)bf16h(v - bf16tof(hh));
      }
      const int fbase = ((ct * 4 + kc) * 2) * 512 + lane * 8;
      *(short8*)&wb[fbase]       = hi;
      *(short8*)&wb[fbase + 512] = lo;
    }
    if (t < 64) wcolp[c * 128 + h * 64 + t] = WS[t * 129 + 128];
  } else {
    // ---- zero ez/iz accumulators (replaces hipMemsetAsync)
    const int zb = b - HB_E - HB_I - AB_BAT - AB_PRE;   // 0..7
    for (int i = zb * 256 + t; i < zquads; i += AB_ZERO * 256)
      zbuf[i] = make_int4(0, 0, 0, 0);
  }
}

// -------------------------------------------------------------------------
// Fused conv chain — R18/R20 geometry (PASSED): 32-row/256-thread/4-wave
// blocks, __launch_bounds__(256,4), chain-pass-split conv with per-kc
// ping-pong B.  R21 delta: per-block degree merge folded into the prologue
// (reads the 48 packed partials directly; merge kernel deleted).
// -------------------------------------------------------------------------
#define ROWS 32

__global__ __launch_bounds__(256, 4) void conv_mfma_kernel(
    const float* __restrict__ x,
    const unsigned int* __restrict__ degp,
    const int* __restrict__ batch,
    const unsigned short* __restrict__ WB, const float* __restrict__ wcolp,
    const float* __restrict__ bu_e1, const float* __restrict__ bu_e2,
    const float* __restrict__ bu_i1, const float* __restrict__ bu_i2,
    float* __restrict__ ez_sum, float* __restrict__ iz_sum, int ncopy)
{
  __shared__ unsigned short XT[2][4096];   // A fragments (bf16), 2 x 8 KB
  __shared__ float degsE[ROWS];
  __shared__ float degsI[ROWS];
  __shared__ int   bg[ROWS];
  __shared__ float redA[ROWS * 4];         // [row][wave]: s1e, then s2e
  __shared__ float redB[ROWS * 4];         // [row][wave]: s1i, then s2i

  const int tid  = threadIdx.x;
  const int lane = tid & 63;
  const int w    = tid >> 6;        // wave 0..3; owns ctA=w, ctB=w+4
  const int n    = lane & 15;
  const int q    = lane >> 4;
  const int mbase = blockIdx.x * ROWS;
  const int cp = blockIdx.x & (ncopy - 1);
  const int jA = w * 16 + n;
  const int jB = (w + 4) * 16 + n;

// Per-kc fragment quad for ONE conv index C: {ctA-hi, ctA-lo, ctB-hi, ctB-lo}
#define LOADP(C, KC, P) do {                                                  \
    const unsigned short* _p = WB + (C) * 32768 + (w * 4 + (KC)) * 1024 + lane * 8; \
    P[0] = *(const short8*)&_p[0];     P[1] = *(const short8*)&_p[512];       \
    P[2] = *(const short8*)&_p[16384]; P[3] = *(const short8*)&_p[16896];     \
  } while (0)

// One kc-step of a single-chain pass on XT[XB] into ACC[rt][s]
#define PSTEP(XB, KC, P, ACC) do {                                            \
    _Pragma("unroll")                                                          \
    for (int rt = 0; rt < 2; ++rt) {                                           \
      const short8 Ah = *(const short8*)&XT[XB][((rt * 4 + (KC)) * 64 + lane) * 8]; \
      f32x4 c0 = ACC[rt][0];                                                   \
      c0 = __builtin_amdgcn_mfma_f32_16x16x32_bf16(Ah, P[0], c0, 0, 0, 0);     \
      c0 = __builtin_amdgcn_mfma_f32_16x16x32_bf16(Ah, P[1], c0, 0, 0, 0);     \
      ACC[rt][0] = c0;                                                         \
      f32x4 c1 = ACC[rt][1];                                                   \
      c1 = __builtin_amdgcn_mfma_f32_16x16x32_bf16(Ah, P[2], c1, 0, 0, 0);     \
      c1 = __builtin_amdgcn_mfma_f32_16x16x32_bf16(Ah, P[3], c1, 0, 0, 0);     \
      ACC[rt][1] = c1;                                                         \
    }                                                                          \
  } while (0)

// Full 4-kc single-chain pass with ping-pong prefetch (Pa/Pb reused)
#define PASS(XB, C, ACC) do {                                                 \
    PSTEP(XB, 0, Pa, ACC);                                                    \
    LOADP(C, 2, Pa);                                                          \
    PSTEP(XB, 1, Pb, ACC);                                                    \
    LOADP(C, 3, Pb);                                                          \
    PSTEP(XB, 2, Pa, ACC);                                                    \
    PSTEP(XB, 3, Pb, ACC);                                                    \
  } while (0)

  // ---- early B prefetch for conv1-E pass (kc 0,1)
  short8 Pa[4], Pb[4];
  LOADP(0, 0, Pa);
  LOADP(0, 1, Pb);
  const float wcE1A = wcolp[0 * 128 + jA], wcE1B = wcolp[0 * 128 + jB];
  const float wcE2A = wcolp[1 * 128 + jA], wcE2B = wcolp[1 * 128 + jB];
  const float wcI1A = wcolp[2 * 128 + jA], wcI1B = wcolp[2 * 128 + jB];
  const float wcI2A = wcolp[3 * 128 + jA], wcI2B = wcolp[3 * 128 + jB];
  const float bE1A = bu_e1[jA], bE1B = bu_e1[jB];
  const float bE2A = bu_e2[jA], bE2B = bu_e2[jB];
  const float bI1A = bu_i1[jA], bI1B = bu_i1[jB];
  const float bI2A = bu_i2[jA], bI2B = bu_i2[jB];

  // ---- stage x -> bf16 A fragments in XT[0], octet-linear (conflict-free)
  #pragma unroll
  for (int u = 0; u < 2; ++u) {
    const int oct  = u * 256 + tid;          // 512 octets
    const int frag = oct >> 6, l = oct & 63;
    const int row  = (frag >> 2) * 16 + (l & 15);
    const int k0   = (frag & 3) * 32 + (l >> 4) * 8;
    const int node = mbase + row;
    float4 a = make_float4(0.f, 0.f, 0.f, 0.f), bb = a;
    if (node < NN) {
      const float* xr = x + (size_t)node * FD + k0;
      a  = *(const float4*)xr;
      bb = *(const float4*)(xr + 4);
    }
    S8 hi;
    hi.u[0] = pk_bf16(a.x, a.y);
    hi.u[1] = pk_bf16(a.z, a.w);
    hi.u[2] = pk_bf16(bb.x, bb.y);
    hi.u[3] = pk_bf16(bb.z, bb.w);
    *(short8*)&XT[0][oct * 8] = hi.s;
  }
  // ---- folded degree merge: 256 threads = 32 nodes x 8 copy-groups.
  // Each thread sums its copy-subset of the packed byte partials (L2-hot,
  // 2.4 MB total), then 8-lane shuffle reduce.  Replaces merge kernel.
  {
    const int node = tid >> 3, c = tid & 7;
    const int gn = mbase + node;
    const bool v = gn < NN;
    const int nc = v ? gn : (NN - 1);
    const int wrd = nc >> 2, sh = 8 * (nc & 3);
    unsigned pe = 0, pi = 0;
    #pragma unroll
    for (int k = 0; k < 4; ++k)
      pe += (degp[(size_t)(c + 8 * k) * DEGB_WORDS + wrd] >> sh) & 255u;
    #pragma unroll
    for (int k = 0; k < 2; ++k)
      pi += (degp[(size_t)(HB_E + c + 8 * k) * DEGB_WORDS + wrd] >> sh) & 255u;
    float fe = (float)pe, fi = (float)pi;
    #pragma unroll
    for (int s = 1; s < 8; s <<= 1) { fe += __shfl_xor(fe, s); fi += __shfl_xor(fi, s); }
    if (c == 0) {
      degsE[node] = v ? fe : 0.f;
      degsI[node] = v ? fi : 0.f;
      bg[node]    = batch[nc];   // clamped: invalid rows inherit last graph
    }
  }
  __syncthreads();   // ---- barrier 1: A fragments + degs + bg visible

  // ================= conv1: pass E, then pass I (ping-pong B) ============
  f32x4 aE[2][2], aI[2][2];
  #pragma unroll
  for (int rt = 0; rt < 2; ++rt)
    #pragma unroll
    for (int s = 0; s < 2; ++s) {
      aE[rt][s] = (f32x4){0.f, 0.f, 0.f, 0.f};
      aI[rt][s] = (f32x4){0.f, 0.f, 0.f, 0.f};
    }
  PASS(0, 0, aE);          // ext conv1
  LOADP(2, 0, Pa);
  LOADP(2, 1, Pb);
  PASS(0, 2, aI);          // int conv1

  // ---- epilogue1: E1 = exp(leaky(acc + b + deg*wc)), f32
  #pragma unroll
  for (int rt = 0; rt < 2; ++rt) {
    const float4 dE = *(const float4*)&degsE[rt * 16 + 4 * q];
    const float4 dI = *(const float4*)&degsI[rt * 16 + 4 * q];
    const float dEv[4] = {dE.x, dE.y, dE.z, dE.w};
    const float dIv[4] = {dI.x, dI.y, dI.z, dI.w};
    #pragma unroll
    for (int r = 0; r < 4; ++r) {
      float v;
      v = aE[rt][0][r] + bE1A + dEv[r] * wcE1A; v = fmaxf(v, 0.01f * v); aE[rt][0][r] = __expf(v);
      v = aE[rt][1][r] + bE1B + dEv[r] * wcE1B; v = fmaxf(v, 0.01f * v); aE[rt][1][r] = __expf(v);
      v = aI[rt][0][r] + bI1A + dIv[r] * wcI1A; v = fmaxf(v, 0.01f * v); aI[rt][0][r] = __expf(v);
      v = aI[rt][1][r] + bI1B + dIv[r] * wcI1B; v = fmaxf(v, 0.01f * v); aI[rt][1][r] = __expf(v);
    }
  }

  // ---- s1 partials: row-sum over this wave's 32 cols (ctA+ctB)
  #pragma unroll
  for (int rt = 0; rt < 2; ++rt) {
    #pragma unroll
    for (int r = 0; r < 4; ++r) {
      float te = aE[rt][0][r] + aE[rt][1][r];
      float ti = aI[rt][0][r] + aI[rt][1][r];
      te += __shfl_xor(te, 1); ti += __shfl_xor(ti, 1);
      te += __shfl_xor(te, 2); ti += __shfl_xor(ti, 2);
      te += __shfl_xor(te, 4); ti += __shfl_xor(ti, 4);
      te += __shfl_xor(te, 8); ti += __shfl_xor(ti, 8);
      if (n == 0) {
        redA[(rt * 16 + q * 4 + r) * 4 + w] = te;
        redB[(rt * 16 + q * 4 + r) * 4 + w] = ti;
      }
    }
  }

  // ---- pack E1 to bf16 pairs; prefetch conv2-ext B (kc 0,1)
  unsigned int pE[2][2][2], pI[2][2][2];
  #pragma unroll
  for (int rt = 0; rt < 2; ++rt)
    #pragma unroll
    for (int s = 0; s < 2; ++s) {
      pE[rt][s][0] = pk_bf16(aE[rt][s][0], aE[rt][s][1]);
      pE[rt][s][1] = pk_bf16(aE[rt][s][2], aE[rt][s][3]);
      pI[rt][s][0] = pk_bf16(aI[rt][s][0], aI[rt][s][1]);
      pI[rt][s][1] = pk_bf16(aI[rt][s][2], aI[rt][s][3]);
    }
  LOADP(1, 0, Pa);
  LOADP(1, 1, Pb);

  // ---- write E1e -> XT[1] in A-fragment order
  #pragma unroll
  for (int rt = 0; rt < 2; ++rt)
    #pragma unroll
    for (int s = 0; s < 2; ++s) {
      const int ct = w + s * 4;
      const int ib = ((rt * 4 + (ct >> 1)) * 64 + ((ct & 1) * 2 + (n >> 3)) * 16 + q * 4) * 8 + (n & 7);
      XT[1][ib]      = (unsigned short)(pE[rt][s][0] & 0xFFFFu);
      XT[1][ib + 8]  = (unsigned short)(pE[rt][s][0] >> 16);
      XT[1][ib + 16] = (unsigned short)(pE[rt][s][1] & 0xFFFFu);
      XT[1][ib + 24] = (unsigned short)(pE[rt][s][1] >> 16);
    }
  __syncthreads();   // ---- barrier 2: XT1 + s1 partials visible; XT0 reads done

  // ---- write E1i -> XT[0] (conv1 reads done)
  #pragma unroll
  for (int rt = 0; rt < 2; ++rt)
    #pragma unroll
    for (int s = 0; s < 2; ++s) {
      const int ct = w + s * 4;
      const int ib = ((rt * 4 + (ct >> 1)) * 64 + ((ct & 1) * 2 + (n >> 3)) * 16 + q * 4) * 8 + (n & 7);
      XT[0][ib]      = (unsigned short)(pI[rt][s][0] & 0xFFFFu);
      XT[0][ib + 8]  = (unsigned short)(pI[rt][s][0] >> 16);
      XT[0][ib + 16] = (unsigned short)(pI[rt][s][1] & 0xFFFFu);
      XT[0][ib + 24] = (unsigned short)(pI[rt][s][1] >> 16);
    }

  // ---- row-owned s1 inverses: lane ℓ&31 owns row ℓ&31
  float s1iE, s1iI;
  {
    const int rl = (lane & 31) * 4;
    const f32x4 a0 = *(const f32x4*)&redA[rl];
    s1iE = frcp((a0[0] + a0[1]) + (a0[2] + a0[3]));
    const f32x4 b0 = *(const f32x4*)&redB[rl];
    s1iI = frcp((b0[0] + b0[1]) + (b0[2] + b0[3]));
  }

  // ================= conv2-ext from XT[1] =================
  f32x4 cE[2][2], cI[2][2];
  #pragma unroll
  for (int rt = 0; rt < 2; ++rt)
    #pragma unroll
    for (int s = 0; s < 2; ++s) cE[rt][s] = (f32x4){0.f, 0.f, 0.f, 0.f};
  PASS(1, 1, cE);          // ext conv2 from XT1
  LOADP(3, 0, Pa);         // conv2-int prefetch (consumed after barrier 3)
  LOADP(3, 1, Pb);
  __syncthreads();   // ---- barrier 3: E1i visible; redA/redB s1-reads done

  // ================= conv2-int from XT[0] =================
  #pragma unroll
  for (int rt = 0; rt < 2; ++rt)
    #pragma unroll
    for (int s = 0; s < 2; ++s) cI[rt][s] = (f32x4){0.f, 0.f, 0.f, 0.f};
  PASS(0, 3, cI);          // int conv2 from XT0

  // ---- epilogue2: logits = U2*inv_s1 + b + deg*wc; E2 = exp(leaky(.));
  //      s2 partials -> redA/redB (safe after b3)
  #pragma unroll
  for (int rt = 0; rt < 2; ++rt) {
    const float4 dE = *(const float4*)&degsE[rt * 16 + 4 * q];
    const float4 dI = *(const float4*)&degsI[rt * 16 + 4 * q];
    const float dEv[4] = {dE.x, dE.y, dE.z, dE.w};
    const float dIv[4] = {dI.x, dI.y, dI.z, dI.w};
    #pragma unroll
    for (int r = 0; r < 4; ++r) {
      const int row = rt * 16 + q * 4 + r;
      const float i1e = __shfl(s1iE, row);
      const float i1i = __shfl(s1iI, row);
      float v;
      v = cE[rt][0][r] * i1e + bE2A + dEv[r] * wcE2A; v = fmaxf(v, 0.01f * v); cE[rt][0][r] = __expf(v);
      v = cE[rt][1][r] * i1e + bE2B + dEv[r] * wcE2B; v = fmaxf(v, 0.01f * v); cE[rt][1][r] = __expf(v);
      v = cI[rt][0][r] * i1i + bI2A + dIv[r] * wcI2A; v = fmaxf(v, 0.01f * v); cI[rt][0][r] = __expf(v);
      v = cI[rt][1][r] * i1i + bI2B + dIv[r] * wcI2B; v = fmaxf(v, 0.01f * v); cI[rt][1][r] = __expf(v);
    }
    #pragma unroll
    for (int r = 0; r < 4; ++r) {
      float te = cE[rt][0][r] + cE[rt][1][r];
      float ti = cI[rt][0][r] + cI[rt][1][r];
      te += __shfl_xor(te, 1); ti += __shfl_xor(ti, 1);
      te += __shfl_xor(te, 2); ti += __shfl_xor(ti, 2);
      te += __shfl_xor(te, 4); ti += __shfl_xor(ti, 4);
      te += __shfl_xor(te, 8); ti += __shfl_xor(ti, 8);
      if (n == 0) {
        redA[(rt * 16 + q * 4 + r) * 4 + w] = te;
        redB[(rt * 16 + q * 4 + r) * 4 + w] = ti;
      }
    }
  }
  __syncthreads();   // ---- barrier 4: s2 partials visible

  // ---- row-owned s2 inverses + normalize
  float s2iE, s2iI;
  {
    const int rl = (lane & 31) * 4;
    const f32x4 a0 = *(const f32x4*)&redA[rl];
    s2iE = frcp((a0[0] + a0[1]) + (a0[2] + a0[3]));
    const f32x4 b0 = *(const f32x4*)&redB[rl];
    s2iI = frcp((b0[0] + b0[1]) + (b0[2] + b0[3]));
  }
  #pragma unroll
  for (int rt = 0; rt < 2; ++rt) {
    #pragma unroll
    for (int r = 0; r < 4; ++r) {
      const int row = rt * 16 + q * 4 + r;
      const float i2e = __shfl(s2iE, row);
      const float i2i = __shfl(s2iI, row);
      cE[rt][0][r] *= i2e; cE[rt][1][r] *= i2e;
      cI[rt][0][r] *= i2i; cI[rt][1][r] *= i2i;
    }
  }

  // ---- scatter into XCD-private per-graph sums (masked per-graph reduce)
  {
    float* __restrict__ ezp = ez_sum + (size_t)cp * EZ_STRIDE;
    float* __restrict__ izp = iz_sum + (size_t)cp * EZ_STRIDE;

    if (mbase + ROWS - 1 >= NN) {   // zero out-of-range rows (last block)
      #pragma unroll
      for (int rt = 0; rt < 2; ++rt)
        #pragma unroll
        for (int r = 0; r < 4; ++r) {
          const int row = rt * 16 + q * 4 + r;
          if (mbase + row >= NN) {
            cE[rt][0][r] = 0.f; cE[rt][1][r] = 0.f;
            cI[rt][0][r] = 0.f; cI[rt][1][r] = 0.f;
          }
        }
    }

    const int g0 = bg[0], g1 = bg[ROWS - 1];
    for (int g = g0; g <= g1; ++g) {
      const bool one = (g0 == g1);
      float seA = 0.f, siA = 0.f, seB = 0.f, siB = 0.f;
      #pragma unroll
      for (int rt = 0; rt < 2; ++rt)
        #pragma unroll
        for (int r = 0; r < 4; ++r) {
          const int row = rt * 16 + q * 4 + r;
          const bool m = one || (bg[row] == g);
          seA += m ? cE[rt][0][r] : 0.f;
          seB += m ? cE[rt][1][r] : 0.f;
          siA += m ? cI[rt][0][r] : 0.f;
          siB += m ? cI[rt][1][r] : 0.f;
        }
      seA += __shfl_xor(seA, 16); siA += __shfl_xor(siA, 16);
      seB += __shfl_xor(seB, 16); siB += __shfl_xor(siB, 16);
      seA += __shfl_xor(seA, 32); siA += __shfl_xor(siA, 32);
      seB += __shfl_xor(seB, 32); siB += __shfl_xor(siB, 32);
      if (q == 0) {
        atomicAdd(&ezp[g * FD + jA], seA);
        atomicAdd(&ezp[g * FD + jB], seB);
        atomicAdd(&izp[g * FD + jA], siA);
        atomicAdd(&izp[g * FD + jB], siB);
      }
    }
  }
#undef LOADP
#undef PSTEP
#undef PASS
}

// -------------------------------------------------------------------------
// Final MLP: 64 blocks (one per graph) x 128 threads.  Sums ncopy ez/iz
// copies and the CNT_SLOTS batch partials.
// -------------------------------------------------------------------------
__global__ __launch_bounds__(128) void fc_kernel(
    const float* __restrict__ ez_sum, const float* __restrict__ iz_sum,
    const int* __restrict__ cnt,
    const float* __restrict__ fc1_w, const float* __restrict__ fc1_b,
    const float* __restrict__ fc2_w, const float* __restrict__ fc2_b,
    float* __restrict__ out, int ncopy)
{
  __shared__ float z[256];
  __shared__ float red2[2];
  const int g = blockIdx.x, t = threadIdx.x;
  int cc = 0;
  #pragma unroll
  for (int c = 0; c < CNT_SLOTS; ++c) cc += cnt[c * 64 + g];
  float se = 0.f, si = 0.f;
  for (int c = 0; c < ncopy; ++c) {
    se += ez_sum[(size_t)c * EZ_STRIDE + g * 128 + t];
    si += iz_sum[(size_t)c * EZ_STRIDE + g * 128 + t];
  }
  const float denom = fmaxf((float)cc, 1.0f);
  z[t]       = se / denom;
  z[128 + t] = si / denom;
  __syncthreads();

  const float* wr = fc1_w + (size_t)t * 256;
  float a = fc1_b[t];
  #pragma unroll 4
  for (int c = 0; c < 256; c += 4) {
    const float4 wv = *(const float4*)(wr + c);
    a += wv.x * z[c] + wv.y * z[c + 1] + wv.z * z[c + 2] + wv.w * z[c + 3];
  }
  a = fmaxf(a, 0.f) * fc2_w[t];
  a += __shfl_xor(a, 1);
  a += __shfl_xor(a, 2);
  a += __shfl_xor(a, 4);
  a += __shfl_xor(a, 8);
  a += __shfl_xor(a, 16);
  a += __shfl_xor(a, 32);
  if ((t & 63) == 0) red2[t >> 6] = a;
  __syncthreads();
  if (t == 0) out[g] = red2[0] + red2[1] + fc2_b[0];
}

// -------------------------------------------------------------------------
extern "C" void kernel_launch(void* const* d_in, const int* in_sizes, int n_in,
                              void* d_out, int out_size, void* d_ws, size_t ws_size,
                              hipStream_t stream) {
  const float* x     = (const float*)d_in[0];
  const int4*  ei4   = (const int4*) d_in[1];   // [2,E]: first E = sources
  const int4*  iei4  = (const int4*) d_in[3];
  const int*   batch = (const int*)  d_in[5];
  const float* wu_e1 = (const float*)d_in[8];
  const float* bu_e1 = (const float*)d_in[9];
  const float* wu_e2 = (const float*)d_in[12];
  const float* bu_e2 = (const float*)d_in[13];
  const float* wu_i1 = (const float*)d_in[16];
  const float* bu_i1 = (const float*)d_in[17];
  const float* wu_i2 = (const float*)d_in[20];
  const float* bu_i2 = (const float*)d_in[21];
  const float* fc1_w = (const float*)d_in[22];
  const float* fc1_b = (const float*)d_in[23];
  const float* fc2_w = (const float*)d_in[24];
  const float* fc2_b = (const float*)d_in[25];

  // Layout (NO pre-zeroed region — every range is fully written per launch):
  // [ez ncopy x 32768][iz ncopy x 32768][cnt 13*256][WB 262144][wcolp 2048]
  // [degp 48 x 50176]
  // Total @ ncopy=8: 524288 + 3328 + 262144 + 2048 + 2408448 = 3,200,256 B
  const size_t need8 = 8ull * 2 * 32768 + CNT_SLOTS * 256 + 262144 + 2048
                     + (size_t)(HB_E + HB_I) * DEGB_WORDS * 4;
  const int ncopy = (ws_size >= need8) ? 8 : 1;

  char* ws = (char*)d_ws;
  size_t off = 0;
  float* ez      = (float*)(ws + off); off += (size_t)ncopy * 32768;
  float* iz      = (float*)(ws + off); off += (size_t)ncopy * 32768;
  const int zquads = (int)(((size_t)ncopy * 2 * 32768) / 16);  // ez+iz int4s
  int*   cnt     = (int*)(ws + off);  off += CNT_SLOTS * 256;
  unsigned short* WB = (unsigned short*)(ws + off); off += 262144;
  float* wcolp   = (float*)(ws + off); off += 2048;
  unsigned int* degp = (unsigned int*)(ws + off);
  off += (size_t)(HB_E + HB_I) * DEGB_WORDS * 4;

  aux_kernel<<<HB_E + HB_I + AB_BAT + AB_PRE + AB_ZERO, 256, 0, stream>>>(
      ei4, iei4, batch, wu_e1, wu_e2, wu_i1, wu_i2,
      degp, cnt, WB, wcolp, (int4*)ez, zquads);

  conv_mfma_kernel<<<dim3((NN + ROWS - 1) / ROWS), 256, 0, stream>>>(
      x, degp, batch, WB, wcolp,
      bu_e1, bu_e2, bu_i1, bu_i2, ez, iz, ncopy);

  fc_kernel<<<NG, 128, 0, stream>>>(ez, iz, cnt, fc1_w, fc1_b, fc2_w, fc2_b,
                                    (float*)d_out, ncopy);
}